// Round 1
// baseline (262.647 us; speedup 1.0000x reference)
//
#include <hip/hip_runtime.h>

// SortPredictionByEta: B=64, V=16384, F=32, C=4
// out[b,v,j] = frac[b,v, perm[b,j]] where perm ranks f by weighted eta ascending.

constexpr int B = 64;
constexpr int V = 16384;
constexpr int F = 32;
constexpr int NCHUNK = 16;          // V-chunks per batch for deterministic reduction
constexpr int CHUNK = V / NCHUNK;   // 1024 rows per block

// ---------------- Kernel 1: partial reductions over V ----------------
// grid = (NCHUNK, B), block = 256.
// Each thread: f-group g = tid&7 (4 consecutive f), v-lane w = tid>>3 (stride 32 over v).
__global__ __launch_bounds__(256) void k_reduce(
    const float* __restrict__ frac, const float* __restrict__ feat,
    float* __restrict__ p1, float* __restrict__ p2)
{
    const int b     = blockIdx.y;
    const int chunk = blockIdx.x;
    const int tid   = threadIdx.x;
    const int g = tid & 7;
    const int w = tid >> 3;
    const int v0 = chunk * CHUNK;

    float4 a1 = make_float4(0.f, 0.f, 0.f, 0.f);
    float4 a2 = make_float4(0.f, 0.f, 0.f, 0.f);

    for (int v = v0 + w; v < v0 + CHUNK; v += 32) {
        const int row = b * V + v;                 // < 1M, fits int
        const float e   = feat[row * 4 + 0];       // broadcast across the 8 g-lanes
        const float eta = feat[row * 4 + 1];
        const float ee  = e * eta;
        const float4 fr = reinterpret_cast<const float4*>(frac)[row * 8 + g];
        a1.x += e  * fr.x; a1.y += e  * fr.y; a1.z += e  * fr.z; a1.w += e  * fr.w;
        a2.x += ee * fr.x; a2.y += ee * fr.y; a2.z += ee * fr.z; a2.w += ee * fr.w;
    }

    __shared__ float red[2][32][33];               // +1 pad: conflict-free reads
    const int f0 = 4 * g;
    red[0][w][f0+0] = a1.x; red[0][w][f0+1] = a1.y; red[0][w][f0+2] = a1.z; red[0][w][f0+3] = a1.w;
    red[1][w][f0+0] = a2.x; red[1][w][f0+1] = a2.y; red[1][w][f0+2] = a2.z; red[1][w][f0+3] = a2.w;
    __syncthreads();

    if (tid < 64) {
        const int which = tid >> 5;
        const int f     = tid & 31;
        float s = 0.f;
        #pragma unroll
        for (int j = 0; j < 32; ++j) s += red[which][j][f];
        float* dst = which ? p2 : p1;
        dst[(b * NCHUNK + chunk) * F + f] = s;
    }
}

// ---------------- Kernel 2: finalize + rank-sort (tiny) ----------------
// grid = (B), block = 64 (one wave; lanes 0..31 active for the 32 f's).
__global__ __launch_bounds__(64) void k_sort(
    const float* __restrict__ p1, const float* __restrict__ p2,
    int* __restrict__ perm)
{
    const int b   = blockIdx.x;
    const int tid = threadIdx.x;
    __shared__ float wv[32];

    if (tid < 32) {
        float s1 = 0.f, s2 = 0.f;
        for (int c = 0; c < NCHUNK; ++c) {
            s1 += p1[(b * NCHUNK + c) * F + tid];
            s2 += p2[(b * NCHUNK + c) * F + tid];
        }
        float we = s2 / (s1 + 1e-7f);
        // jnp.where(|we|>0.1, we, 500); NaN compares false -> 500 (matches jnp)
        we = (fabsf(we) > 0.1f) ? we : 500.0f;
        wv[tid] = we;
    }
    __syncthreads();

    if (tid < 32) {
        const float my = wv[tid];
        int rank = 0;
        #pragma unroll
        for (int j = 0; j < 32; ++j) {
            const float vj = wv[j];
            // ascending by value; ties broken by lower index first (top_k stability)
            rank += (vj < my || (vj == my && j < tid)) ? 1 : 0;
        }
        perm[b * F + rank] = tid;   // ranked_indices[b][rank] = tid
    }
}

// ---------------- Kernel 3: apply permutation ----------------
// grid = (V/128, B), block = 256. Each thread writes 4 float4 rows-chunks.
// Gathers land inside the same 128B row -> full cacheline use; writes coalesced.
__global__ __launch_bounds__(256) void k_permute(
    const float* __restrict__ frac, const int* __restrict__ perm,
    float* __restrict__ out)
{
    const int b = blockIdx.y;
    __shared__ int pm[32];
    if (threadIdx.x < 32) pm[threadIdx.x] = perm[b * F + threadIdx.x];
    __syncthreads();

    const int tid = threadIdx.x;
    const int q = tid & 7;     // which float4 of the 32-float row
    const int r = tid >> 3;    // row 0..31 within a 32-row group
    const int i0 = pm[4*q+0], i1 = pm[4*q+1], i2 = pm[4*q+2], i3 = pm[4*q+3];

    const int vbase = blockIdx.x * 128;
    #pragma unroll
    for (int it = 0; it < 4; ++it) {
        const int v = vbase + it * 32 + r;
        const int row = b * V + v;                      // (row*32) < 2^31, safe
        const float* src = frac + (size_t)row * F;
        float4 o;
        o.x = src[i0]; o.y = src[i1]; o.z = src[i2]; o.w = src[i3];
        reinterpret_cast<float4*>(out)[row * 8 + q] = o;
    }
}

extern "C" void kernel_launch(void* const* d_in, const int* in_sizes, int n_in,
                              void* d_out, int out_size, void* d_ws, size_t ws_size,
                              hipStream_t stream)
{
    const float* frac = (const float*)d_in[0];   // (B,V,F) f32
    const float* feat = (const float*)d_in[1];   // (B,V,C) f32
    float* out = (float*)d_out;                  // (B,V,F) f32

    // workspace layout: p1[B][NCHUNK][F], p2[B][NCHUNK][F], perm[B][F]  (~270 KB)
    float* p1   = (float*)d_ws;
    float* p2   = p1 + B * NCHUNK * F;
    int*   perm = (int*)(p2 + B * NCHUNK * F);

    k_reduce <<<dim3(NCHUNK, B), 256, 0, stream>>>(frac, feat, p1, p2);
    k_sort   <<<dim3(B),          64, 0, stream>>>(p1, p2, perm);
    k_permute<<<dim3(V / 128, B), 256, 0, stream>>>(frac, perm, out);
}

// Round 2
// 260.973 us; speedup vs baseline: 1.0064x; 1.0064x over previous
//
#include <hip/hip_runtime.h>

// SortPredictionByEta: B=64, V=16384, F=32, C=4
// out[b,v,j] = frac[b,v, perm[b,j]] where perm ranks f by weighted eta ascending.

constexpr int B = 64;
constexpr int V = 16384;
constexpr int F = 32;
constexpr int NCHUNK = 16;          // V-chunks per batch for deterministic reduction
constexpr int CHUNK = V / NCHUNK;   // 1024 rows per block

// ---------------- Kernel 1: partial reductions over V ----------------
// grid = (NCHUNK, B), block = 256.
// Stage (e, e*eta) per row into LDS once (kills the 8x-duplicated scalar feat
// loads of R1), then f-group g = tid&7 covers 4 consecutive f, v-lane w = tid>>3
// strides 32 over v. Summation order identical to R1 (bit-exact ranking).
__global__ __launch_bounds__(256) void k_reduce(
    const float* __restrict__ frac, const float* __restrict__ feat,
    float* __restrict__ p1, float* __restrict__ p2)
{
    const int b     = blockIdx.y;
    const int chunk = blockIdx.x;
    const int tid   = threadIdx.x;
    const int v0    = chunk * CHUNK;

    __shared__ float2 sfeat[CHUNK];                // 8 KiB: {e, e*eta} per row
    const float4* feat4 = reinterpret_cast<const float4*>(feat);
    #pragma unroll
    for (int i = 0; i < CHUNK / 256; ++i) {
        const int r = tid + i * 256;
        const float4 f = feat4[b * V + v0 + r];    // coalesced 16B/lane
        sfeat[r] = make_float2(f.x, f.x * f.y);
    }
    __syncthreads();

    const int g = tid & 7;
    const int w = tid >> 3;
    float4 a1 = make_float4(0.f, 0.f, 0.f, 0.f);
    float4 a2 = make_float4(0.f, 0.f, 0.f, 0.f);
    const float4* frac4 = reinterpret_cast<const float4*>(frac);

    for (int r = w; r < CHUNK; r += 32) {
        const float2 ee = sfeat[r];                // broadcast across 8 g-lanes
        const float4 fr = frac4[(b * V + v0 + r) * 8 + g];
        a1.x += ee.x * fr.x; a1.y += ee.x * fr.y; a1.z += ee.x * fr.z; a1.w += ee.x * fr.w;
        a2.x += ee.y * fr.x; a2.y += ee.y * fr.y; a2.z += ee.y * fr.z; a2.w += ee.y * fr.w;
    }

    __shared__ float red[2][32][33];               // +1 pad: conflict-free reads
    const int f0 = 4 * g;
    red[0][w][f0+0] = a1.x; red[0][w][f0+1] = a1.y; red[0][w][f0+2] = a1.z; red[0][w][f0+3] = a1.w;
    red[1][w][f0+0] = a2.x; red[1][w][f0+1] = a2.y; red[1][w][f0+2] = a2.z; red[1][w][f0+3] = a2.w;
    __syncthreads();

    if (tid < 64) {
        const int which = tid >> 5;
        const int f     = tid & 31;
        float s = 0.f;
        #pragma unroll
        for (int j = 0; j < 32; ++j) s += red[which][j][f];
        float* dst = which ? p2 : p1;
        dst[(b * NCHUNK + chunk) * F + f] = s;
    }
}

// ---------------- Kernel 2: finalize + rank + permute ----------------
// grid = (V/64, B), block = 256. Each block redundantly recomputes its batch's
// 32-wide rank (4 KiB of L2-hot p1/p2 reads), stages a 64-row tile in LDS via
// coalesced float4, permutes through LDS scalar reads, stores float4.
__global__ __launch_bounds__(256) void k_permute(
    const float* __restrict__ frac,
    const float* __restrict__ p1, const float* __restrict__ p2,
    float* __restrict__ out)
{
    const int b   = blockIdx.y;
    const int tid = threadIdx.x;

    __shared__ float wv[32];
    __shared__ int   pm[32];
    __shared__ float tile[64 * 36];                // stride 36: 16B-aligned rows, spread banks

    if (tid < 32) {
        float s1 = 0.f, s2 = 0.f;
        #pragma unroll
        for (int c = 0; c < NCHUNK; ++c) {
            s1 += p1[(b * NCHUNK + c) * F + tid];
            s2 += p2[(b * NCHUNK + c) * F + tid];
        }
        float we = s2 / (s1 + 1e-7f);
        // jnp.where(|we|>0.1, we, 500); NaN compares false -> 500 (matches jnp)
        we = (fabsf(we) > 0.1f) ? we : 500.0f;
        wv[tid] = we;
    }
    __syncthreads();
    if (tid < 32) {
        const float my = wv[tid];
        int rank = 0;
        #pragma unroll
        for (int j = 0; j < 32; ++j) {
            const float vj = wv[j];
            // ascending; ties broken by lower index first (top_k stability)
            rank += (vj < my || (vj == my && j < tid)) ? 1 : 0;
        }
        pm[rank] = tid;
    }

    const int vbase = blockIdx.x * 64;
    const float4* frac4 = reinterpret_cast<const float4*>(frac);
    #pragma unroll
    for (int i = 0; i < 2; ++i) {
        const int idx = tid + i * 256;             // 0..511 float4s of the tile
        const int r = idx >> 3, q = idx & 7;
        const float4 v = frac4[(b * V + vbase + r) * 8 + q];
        *reinterpret_cast<float4*>(&tile[r * 36 + q * 4]) = v;
    }
    __syncthreads();                               // covers pm + tile

    #pragma unroll
    for (int i = 0; i < 2; ++i) {
        const int idx = tid + i * 256;
        const int r = idx >> 3, q = idx & 7;
        const int j0 = pm[4*q+0], j1 = pm[4*q+1], j2 = pm[4*q+2], j3 = pm[4*q+3];
        float4 o;
        o.x = tile[r * 36 + j0];
        o.y = tile[r * 36 + j1];
        o.z = tile[r * 36 + j2];
        o.w = tile[r * 36 + j3];
        reinterpret_cast<float4*>(out)[(b * V + vbase + r) * 8 + q] = o;
    }
}

extern "C" void kernel_launch(void* const* d_in, const int* in_sizes, int n_in,
                              void* d_out, int out_size, void* d_ws, size_t ws_size,
                              hipStream_t stream)
{
    const float* frac = (const float*)d_in[0];   // (B,V,F) f32
    const float* feat = (const float*)d_in[1];   // (B,V,C) f32
    float* out = (float*)d_out;                  // (B,V,F) f32

    // workspace: p1[B][NCHUNK][F], p2[B][NCHUNK][F]  (256 KiB)
    float* p1 = (float*)d_ws;
    float* p2 = p1 + B * NCHUNK * F;

    k_reduce <<<dim3(NCHUNK, B), 256, 0, stream>>>(frac, feat, p1, p2);
    k_permute<<<dim3(V / 64, B), 256, 0, stream>>>(frac, p1, p2, out);
}